// Round 6
// baseline (228.598 us; speedup 1.0000x reference)
//
#include <hip/hip_runtime.h>

// CollisionLoss: B x (7 left) x (7 right) segment-segment squared distances,
// masked exp(-d2) sum / B.
// R6: attack latency-boundedness. R3/R4/R5 (very different inner structures)
// all plateau at kernel ~62us vs ~13us VALU / ~12us HBM floors; the shared
// invariant is 1 thread/batch -> 4096 waves = 4 waves/SIMD, too few to hide
// the ~900cyc rot-gather misses and serialize-free the compute. Now 7
// threads/batch: wave w of a 448-thread block owns right-segment row i=w for
// 64 batches (lane = local batch). 28672 waves = 28 waves/SIMD. Left nodes
// (shared by the 7 pairs of a thread) come from the LDS pos mirror; rot
// gather is 1 dword/thread semi-coalesced (waves 0..5) into an LDS aux.
// Branchless Ericson cascade unchanged (exact since R2).

__device__ __forceinline__ float rcpf(float x) { return __builtin_amdgcn_rcpf(x); }
__device__ __forceinline__ float clamp01(float x) {
    return __builtin_amdgcn_fmed3f(x, 0.0f, 1.0f);
}

__device__ __forceinline__ float cap_dist2(
    float px0, float py0, float pz0, float px1, float py1, float pz1,
    float qx0, float qy0, float qz0, float qx1, float qy1, float qz1)
{
    const float dpx = px1 - px0, dpy = py1 - py0, dpz = pz1 - pz0;
    const float dqx = qx1 - qx0, dqy = qy1 - qy0, dqz = qz1 - qz0;
    const float rx  = px0 - qx0, ry  = py0 - qy0, rz  = pz0 - qz0;

    const float a = dpx*dpx + dpy*dpy + dpz*dpz;   // >0 w.p. 1 (gaussian)
    const float c = dqx*dqx + dqy*dqy + dqz*dqz;   // >0 w.p. 1
    const float b = dpx*dqx + dpy*dqy + dpz*dqz;
    const float d = dpx*rx + dpy*ry + dpz*rz;
    const float e = dqx*rx + dqy*ry + dqz*rz;
    const float det = a*c - b*b;

    const float rcp_a = rcpf(a);
    const float rcp_c = rcpf(c);

    // s0 = det>0 ? clamp01((be-cd)/det) : 0  (cndmask kills the inf/NaN path)
    const float f  = b*e - c*d;
    const float s0 = (det > 0.0f) ? clamp01(f * rcpf(det)) : 0.0f;

    const float tn = b*s0 + e;                 // t numerator (denominator c)
    const float t  = clamp01(tn * rcp_c);

    // recompute s only where t was clamped; ties are measure-zero
    const float sA = clamp01(-d * rcp_a);          // t clamped to 0
    const float sB = clamp01((b - d) * rcp_a);     // t clamped to 1
    const float s  = (tn < 0.0f) ? sA : ((tn > c) ? sB : s0);

    const float wx = rx + s*dpx - t*dqx;
    const float wy = ry + s*dpy - t*dqy;
    const float wz = rz + s*dpz - t*dqz;
    return wx*wx + wy*wy + wz*wz;
}

#define BT   448   // 7 waves per block
#define BPB  64    // batches per block (= lanes per wave)

__global__ __launch_bounds__(BT) void collision_loss_kernel(
    const float* __restrict__ pos,
    const float* __restrict__ rot,
    float* __restrict__ out)
{
    __shared__ float slab[BPB * 42];   // 64 batches' pos rows, linear mirror
    __shared__ float aux [BPB * 6];    // per batch: r6.xyz (node6 col2), rd.xyz
    __shared__ float wsum[7];

    const int tid       = threadIdx.x;
    const int blockBase = blockIdx.x * BPB;

    // ---- coalesced pos stage: 1344 float2 = 3 per thread, lanes consecutive
    const float2* g2 = reinterpret_cast<const float2*>(pos + (size_t)blockBase * 42);
    float2*       s2 = reinterpret_cast<float2*>(slab);
    #pragma unroll
    for (int k = 0; k < 3; ++k) {
        const int idx = k * BT + tid;          // 0..1343 exact
        s2[idx] = g2[idx];
    }

    // ---- rot gather: waves 0..5 (wave-uniform branch), 1 dword per thread.
    // 64 lanes span ~11 batch rows -> ~21 cache lines/wave vs 64-line scatter.
    if (tid < BPB * 6) {
        const int batch = tid / 6;             // 0..63 (magic-mul)
        const int comp  = tid - 6 * batch;     // 0..5
        // comp 0..2 -> row floats 56,59,62 (node 6 col2); 3..5 -> 119,122,125
        const int off   = (comp < 3) ? (56 + 3 * comp) : (110 + 3 * comp);
        aux[tid] = rot[(size_t)(blockBase + batch) * 126 + off];
    }
    __syncthreads();

    const int w = tid >> 6;    // wave id == right-segment row i (0..6)
    const int l = tid & 63;    // lane == local batch

    // ---- left nodes of lane's batch from LDS (stride 42 floats: 4-way
    // bank alias on b64 = 1.58x, negligible op count) ----
    const float2* m2 = reinterpret_cast<const float2*>(slab) + l * 21;
    const float*  mf = slab + l * 42;
    const float*  ax = aux  + l * 6;
    const float2 u0 = m2[0], u1 = m2[1], u2 = m2[2], u3 = m2[3], u4 = m2[4];
    const float2 u5 = m2[5], u6 = m2[6], u7 = m2[7], u8 = m2[8], u9 = m2[9];
    const float n6z = mf[20];

    const float n0x=u0.x, n0y=u0.y, n0z=u1.x;
    const float n1x=u1.y, n1y=u2.x, n1z=u2.y;
    const float n2x=u3.x, n2y=u3.y, n2z=u4.x;
    const float n3x=u4.y, n3y=u5.x, n3z=u5.y;
    const float n4x=u6.x, n4y=u6.y, n4z=u7.x;
    const float n5x=u7.y, n5y=u8.x, n5z=u8.y;
    const float n6x=u9.x, n6y=u9.y;            // n6z above

    const float hlx = n6x + 0.2f * ax[0];      // handL = node6 + 0.2*col2
    const float hly = n6y + 0.2f * ax[1];
    const float hlz = n6z + 0.2f * ax[2];

    // ---- this wave's right segment: q0 = node 7+w, q1 = node 8+w | handR
    const int qb = 21 + 3 * w;                 // wave-uniform offset
    const float q0x = mf[qb], q0y = mf[qb + 1], q0z = mf[qb + 2];
    float q1x, q1y, q1z;
    if (w < 6) {                               // wave-uniform branch
        q1x = mf[qb + 3]; q1y = mf[qb + 4]; q1z = mf[qb + 5];
    } else {                                   // handR = node13 + 0.2*col2
        q1x = q0x + 0.2f * ax[3];
        q1y = q0y + 0.2f * ax[4];
        q1z = q0z + 0.2f * ax[5];
    }

    float sum = 0.0f;

    auto acc = [&](float p0x, float p0y, float p0z,
                   float p1x, float p1y, float p1z, bool special) {
        const float d2 = cap_dist2(p0x,p0y,p0z, p1x,p1y,p1z,
                                   q0x,q0y,q0z, q1x,q1y,q1z);
        const bool m = special ? (d2 > 0.09f)
                               : ((d2 < 0.01f) && (d2 > 0.0f));
        sum += m ? __expf(-d2) : 0.0f;
    };

    // 7 left segments vs this wave's right segment (special only wave 6, j=6)
    acc(n0x,n0y,n0z, n1x,n1y,n1z, false);
    acc(n1x,n1y,n1z, n2x,n2y,n2z, false);
    acc(n2x,n2y,n2z, n3x,n3y,n3z, false);
    acc(n3x,n3y,n3z, n4x,n4y,n4z, false);
    acc(n4x,n4y,n4z, n5x,n5y,n5z, false);
    acc(n5x,n5y,n5z, n6x,n6y,n6z, false);
    acc(n6x,n6y,n6z, hlx,hly,hlz, w == 6);

    // ---- reduction: wave shuffle -> LDS -> one atomic per block ----
    #pragma unroll
    for (int off = 32; off > 0; off >>= 1)
        sum += __shfl_down(sum, off, 64);
    if (l == 0) wsum[w] = sum;
    __syncthreads();
    if (tid == 0) {
        const float s = ((wsum[0] + wsum[1]) + (wsum[2] + wsum[3]))
                      + ((wsum[4] + wsum[5]) + wsum[6]);
        atomicAdd(out, s * (1.0f / 262144.0f));   // exact pow2 scale = /B
    }
}

extern "C" void kernel_launch(void* const* d_in, const int* in_sizes, int n_in,
                              void* d_out, int out_size, void* d_ws, size_t ws_size,
                              hipStream_t stream) {
    const float* pos = (const float*)d_in[0];   // (B,14,3) f32
    const float* rot = (const float*)d_in[1];   // (B,14,9) f32
    float* out = (float*)d_out;

    const int B = in_sizes[0] / 42;             // 262144 (multiple of 64)
    hipMemsetAsync(out, 0, sizeof(float), stream);

    collision_loss_kernel<<<B / BPB, BT, 0, stream>>>(pos, rot, out);
}